// Round 9
// baseline (128.485 us; speedup 1.0000x reference)
//
#include <hip/hip_runtime.h>
#include <hip/hip_bf16.h>

// VarFlowLoss on MI355X (gfx950) — round 9
// gemm1: r7 base + latency fix. B-LDS eliminated (fragments loaded per-tap straight from
// L2-resident WT1); A double-buffered so the fp32 gather issued at chunk top is consumed
// only AFTER the 144-MFMA compute phase. Zero outstanding VMEM at every __syncthreads ->
// the compiler's vmcnt(0) barrier drain is free. 50.7KB LDS, 2 blocks/CU.

typedef __attribute__((ext_vector_type(4))) float f32x4;
typedef __attribute__((ext_vector_type(8))) short s16x8;

#define DEVFN __device__ __forceinline__

DEVFN float bf2f(unsigned short u){
  unsigned int x = ((unsigned int)u) << 16;
  float f; __builtin_memcpy(&f, &x, 4); return f;
}
DEVFN unsigned short f2bf(float f){
  unsigned int x; __builtin_memcpy(&x, &f, 4);
  x += 0x7fffu + ((x >> 16) & 1u);   // RNE
  return (unsigned short)(x >> 16);
}

#define ASYNC16(gp, lp) __builtin_amdgcn_global_load_lds( \
    (const __attribute__((address_space(1))) unsigned int*)(gp), \
    (__attribute__((address_space(3))) unsigned int*)(lp), 16, 0, 0)

// ---------------- weights transform ----------------
__global__ void k_weights(const float* __restrict__ Watt, const float* __restrict__ Wpost,
                          unsigned short* __restrict__ WT1, unsigned short* __restrict__ WT2){
  const int t = blockIdx.x * 256 + threadIdx.x;
  const int n1 = 9 * 64 * 256;
  if (t < n1){
    const int tap = t / (64 * 256);
    const int rem = t % (64 * 256);
    const int oc = rem / 256, ic = rem % 256;
    WT1[t] = f2bf(Watt[(oc * 256 + ic) * 9 + tap]);
  }
  const int n2 = 9 * 16 * 64;
  if (t < n2){
    const int tap = t / (16 * 64);
    const int rem = t % (16 * 64);
    const int od = rem / 64, ic = rem % 64;
    const float v = (od < 10) ? Wpost[(od * 64 + ic) * 9 + tap] : 0.0f;
    WT2[t] = f2bf(v);
  }
}

// ---------------- borders: out=0 + patch border log-sums ----------------
__global__ void k_borders(const float* __restrict__ gts, float* __restrict__ S,
                          float* __restrict__ out){
  const int bid = blockIdx.x, tid = threadIdx.x;
  if (bid == 0 && tid == 0) *out = 0.0f;
  __shared__ float slab[4096];
  const int rel = bid;                  // = b*64 + py
  const float* gp = gts + (size_t)rel * 4096;
#pragma unroll
  for (int it = 0; it < 4; ++it){
    const int id = it * 256 + tid;
    *(f32x4*)&slab[id * 4] = *(const f32x4*)&gp[id * 4];
  }
  __syncthreads();
  const int px = tid & 63, border = tid >> 6;   // border wave-uniform
  float s = 0.0f;
#pragma unroll
  for (int i = 0; i < 8; ++i){
    float v;
    if (border == 0)      v = slab[px * 8 + i];
    else if (border == 1) v = slab[7 * 512 + px * 8 + i];
    else if (border == 2) v = slab[i * 512 + px * 8];
    else                  v = slab[i * 512 + px * 8 + 7];
    v = ((v > 0.1f) && (v < 80.0f)) ? v : 0.0f;
    s += __logf(v + 1e-6f);
  }
  S[((size_t)rel * 64 + px) * 4 + border] = s;
}

// ---------------- GEMM1: fused transpose + att conv + sigmoid * depth ----------------
// 512 blocks x 256 threads (4 waves). BM=256 (4 y-rows), BK=32, 8 chunks.
// A: dbuf [2][6 yy][66 xp][32 ic] bf16, zero cols xp=0,65, reg-staged fp32->bf16, swizzled.
// B: NO LDS — fragments loaded per-tap from L2-resident WT1 (global_load_dwordx4).
// Per chunk: issue A-loads(c+1) -> compute(c) -> cvt+write(c+1) -> one __syncthreads.
// At the barrier all VMEM is consumed, so the implicit vmcnt(0) drain is free.
__global__ __launch_bounds__(256, 2) void k_gemm1(
    const float* __restrict__ feat,             // NCHW fp32 [B][256][64][64]
    const unsigned short* __restrict__ WT1,     // [9][64][256]
    const float* __restrict__ batt,
    const float* __restrict__ depth,            // NCHW fp32 [B][64][64][64]
    unsigned short* __restrict__ adT)           // [B*4096][64]
{
  __shared__ unsigned short As[2][6 * 66 * 32];   // 2 x 25344 B
  const int t = threadIdx.x;
  const int l = t & 63, w = t >> 6;            // wave w = output y-row / A ic-octet for staging
  const int b = blockIdx.x >> 4, ytile = blockIdx.x & 15;
  const int y0 = ytile * 4;
  const int fr = l & 15, g = l >> 4;
  const int x = l;                             // 0..63

  f32x4 acc[4][4];
#pragma unroll
  for (int i = 0; i < 4; ++i)
#pragma unroll
    for (int j = 0; j < 4; ++j)
#pragma unroll
      for (int q = 0; q < 4; ++q) acc[i][j][q] = 0.0f;

  // zero x-halo columns (xp=0,65) in BOTH buffers: 96 thr = 2 buf x 6 yy x 2 xp x 4 slots
  if (t < 96){
    const int d = t / 48, r = t % 48;
    const int yy = r >> 3, k = r & 7;
    const int xp = (k & 1) ? 65 : 0;
    s16x8 z = {0,0,0,0,0,0,0,0};
    *(s16x8*)&As[d][(yy * 66 + xp) * 32 + (k >> 1) * 8] = z;
  }

  const int xp = x + 1;
  const int sx = (xp >> 1) & 3;

  auto loadA = [&](int c, float* rr){
#pragma unroll
    for (int j = 0; j < 6; ++j){               // j = yy
      const int yr = y0 - 1 + j;
      if (yr >= 0 && yr < 64){
        const float* gp = feat + ((size_t)(b * 256 + c * 32 + w * 8)) * 4096
                               + (size_t)yr * 64 + x;
#pragma unroll
        for (int e = 0; e < 8; ++e) rr[j * 8 + e] = gp[(size_t)e * 4096];
      } else {
#pragma unroll
        for (int e = 0; e < 8; ++e) rr[j * 8 + e] = 0.0f;
      }
    }
  };
  auto cvtWriteA = [&](int d, const float* rr){
#pragma unroll
    for (int j = 0; j < 6; ++j){
      s16x8 v;
#pragma unroll
      for (int e = 0; e < 8; ++e) v[e] = (short)f2bf(rr[j * 8 + e]);
      *(s16x8*)&As[d][(j * 66 + xp) * 32 + ((w ^ sx) * 8)] = v;
    }
  };
  auto compute = [&](const unsigned short* Ab, int c){
#pragma unroll
    for (int tap = 0; tap < 9; ++tap){
      const int dy = tap / 3 - 1, dxp = tap % 3;     // dx+1
      const int r = fr + dxp;                        // xp of fragment base
      const int slotA = (g ^ ((r >> 1) & 3)) * 8;    // +16 in xp keeps (>>1)&3 invariant
      const int rowb = ((w + dy + 1) * 66 + r) * 32 + slotA;
      s16x8 af[4], bfr[4];
#pragma unroll
      for (int j = 0; j < 4; ++j)                    // B straight from L2
        bfr[j] = *(const s16x8*)&WT1[(size_t)(tap * 64 + j * 16 + fr) * 256 + c * 32 + g * 8];
#pragma unroll
      for (int i = 0; i < 4; ++i) af[i] = *(const s16x8*)&Ab[rowb + i * 512];
#pragma unroll
      for (int i = 0; i < 4; ++i)
#pragma unroll
        for (int j = 0; j < 4; ++j)
          acc[i][j] = __builtin_amdgcn_mfma_f32_16x16x32_bf16(af[i], bfr[j], acc[i][j], 0, 0, 0);
    }
  };

  // prologue: chunk 0 into buffer 0 (cvt has no cover once — acceptable)
  float rr[48];
  loadA(0, rr);
  cvtWriteA(0, rr);
  __syncthreads();

  for (int c = 0; c < 8; ++c){
    const int cur = c & 1;
    if (c < 7) loadA(c + 1, rr);       // issue early: compute(c) covers the latency
    compute(As[cur], c);
    if (c < 7) cvtWriteA(cur ^ 1, rr); // vmcnt wait lands here, ~2000 cyc after issue
    __syncthreads();                   // nothing outstanding -> drain is free
  }

  // epilogue: att = sigmoid(acc + b); adT = att * depth
  const int y = y0 + w;
#pragma unroll
  for (int j = 0; j < 4; ++j){
    const int oc = j * 16 + fr;
    const float bb = batt[oc];
    const float* dpt = depth + ((size_t)(b * 64 + oc)) * 4096 + (size_t)y * 64;
    unsigned short* op = adT + ((size_t)(b * 4096 + y * 64)) * 64 + oc;
#pragma unroll
    for (int i = 0; i < 4; ++i){
#pragma unroll
      for (int q = 0; q < 4; ++q){
        const int xo = i * 16 + g * 4 + q;
        const float v = acc[i][j][q] + bb;
        const float att = 1.0f / (1.0f + __expf(-v));
        op[(size_t)xo * 64] = f2bf(att * dpt[xo]);
      }
    }
  }
}

// ---------------- GEMM2: post conv + fused smooth-L1 loss ----------------
DEVFN float sel4(f32x4 v, int i){
  const float ab = (i & 1) ? v[1] : v[0];
  const float cd = (i & 1) ? v[3] : v[2];
  return (i & 2) ? cd : ab;
}

__global__ __launch_bounds__(512, 2) void k_gemm2(
    const unsigned short* __restrict__ adT,     // [B*4096][64]
    const unsigned short* __restrict__ WT2,     // [9][16][64]
    const float* __restrict__ bpost,
    const f32x4* __restrict__ S,                // [B*4096] {Sn,Ss,Sw,Se}
    float* __restrict__ out)
{
  __shared__ unsigned short As[2][20480];   // 80 KB, source-swizzled
  __shared__ unsigned short Bs[9216];       // full B resident (18 KB), source-swizzled
  __shared__ float ps[8];
  const int t = threadIdx.x;
  const int l = t & 63, w = t >> 6;
  const int b = blockIdx.x >> 3, ytile = blockIdx.x & 7;
  const int y0 = ytile * 8;
  const int fr = l & 15, g = l >> 4;

  f32x4 acc[4];
#pragma unroll
  for (int i = 0; i < 4; ++i)
#pragma unroll
    for (int q = 0; q < 4; ++q) acc[i][q] = 0.0f;

  auto stageA = [&](int c, int d){
#pragma unroll
    for (int it2 = 0; it2 < 5; ++it2){
      const int it = it2 * 2 + (t >> 8);
      const int yy = y0 - 1 + it;
      const int xx = (t >> 2) & 63, icg = t & 3;
      unsigned short* lp = &As[d][(it * 64 + xx) * 32 + icg * 8];
      if (yy >= 0 && yy < 64){
        const int sg = icg ^ ((xx >> 1) & 3);        // source-slot swizzle
        const unsigned short* gp = adT
            + ((size_t)(b * 4096 + yy * 64 + xx)) * 64 + c * 32 + sg * 8;
        ASYNC16(gp, lp);
      } else {
        s16x8 z = {0,0,0,0,0,0,0,0};
        *(s16x8*)lp = z;
      }
    }
  };
  // stage all of B once (144 rows x 128B), 16B slots XOR'd by row&7
#pragma unroll
  for (int it = 0; it < 3; ++it){
    const int idx = it * 512 + t;
    if (idx < 1152){
      const int row = idx >> 3, p = idx & 7;
      const int sg = p ^ (row & 7);
      ASYNC16(WT2 + (size_t)row * 64 + sg * 8, Bs + (size_t)idx * 8);
    }
  }
  stageA(0, 0);
  __syncthreads();

  for (int c = 0; c < 2; ++c){
    if (c == 0) stageA(1, 1);
    const unsigned short* Ab = As[c];
    const int pB = ((c * 4 + g) ^ (fr & 7)) * 8;
    for (int tap = 0; tap < 9; ++tap){
      const int dy = tap / 3 - 1, dx = tap % 3 - 1;
      s16x8 af[4];
#pragma unroll
      for (int i = 0; i < 4; ++i){
        const int xv = i * 16 + fr + dx;
        const bool valid = (xv >= 0) && (xv < 64);
        const int xw = valid ? xv : 0;
        const int slot = (g ^ ((xw >> 1) & 3)) * 8;
        s16x8 v = *(const s16x8*)&Ab[((w + dy + 1) * 64 + xw) * 32 + slot];
        s16x8 z = {0,0,0,0,0,0,0,0};
        af[i] = valid ? v : z;
      }
      const s16x8 bfr = *(const s16x8*)&Bs[(tap * 16 + fr) * 64 + pB];
#pragma unroll
      for (int i = 0; i < 4; ++i)
        acc[i] = __builtin_amdgcn_mfma_f32_16x16x32_bf16(af[i], bfr, acc[i], 0, 0, 0);
    }
    __syncthreads();
  }

  // fused loss epilogue
  const unsigned aPack = (3u<<0)|(1u<<2)|(3u<<4)|(1u<<6)|(2u<<8)|(0u<<10)|(1u<<12)|(3u<<14)|(0u<<16)|(2u<<18);
  const unsigned bPack = (2u<<0)|(0u<<2)|(3u<<4)|(1u<<6)|(2u<<8)|(0u<<10)|(1u<<12)|(3u<<14)|(0u<<16)|(2u<<18);
  float lsum = 0.0f;
  const int y = y0 + w;
  if (fr < 10){
    const int od = fr;
    const int ai = (aPack >> (2 * od)) & 3;
    const int bi = (bPack >> (2 * od)) & 3;
    const bool xshift = (od & 1) == 0;
    const float bp = bpost[od];
#pragma unroll
    for (int i = 0; i < 4; ++i){
#pragma unroll
      for (int q = 0; q < 4; ++q){
        const int xo = i * 16 + g * 4 + q;
        const size_t gm = (size_t)b * 4096 + (size_t)y * 64 + xo;
        const f32x4 sa = S[gm];
        const bool nb = xshift ? (xo < 63) : (y < 63);
        const size_t ga = xshift ? (nb ? gm + 1 : gm) : (nb ? gm + 64 : gm);
        const f32x4 sbv = S[ga];
        const float sbf = nb ? sel4(sbv, bi) : 0.0f;
        const float flow = (sel4(sa, ai) - sbf) * 0.125f;
        const float dv = acc[i][q] + bp - flow;
        const float adv = fabsf(dv);
        lsum += (adv < 0.01f) ? (50.0f * dv * dv) : (adv - 0.005f);
      }
    }
  }
#pragma unroll
  for (int off = 32; off > 0; off >>= 1) lsum += __shfl_down(lsum, off);
  if (l == 0) ps[w] = lsum;
  __syncthreads();
  if (t == 0){
    float s = 0.0f;
#pragma unroll
    for (int i = 0; i < 8; ++i) s += ps[i];
    atomicAdd(out, s * (1.0f / 1310720.0f));
  }
}

// ---------------- launch ----------------
extern "C" void kernel_launch(void* const* d_in, const int* in_sizes, int n_in,
                              void* d_out, int out_size, void* d_ws, size_t ws_size,
                              hipStream_t stream){
  const float* feat  = (const float*)d_in[0];
  const float* depth = (const float*)d_in[1];
  const float* gts   = (const float*)d_in[2];
  const float* Watt  = (const float*)d_in[3];
  const float* batt  = (const float*)d_in[4];
  const float* Wpost = (const float*)d_in[5];
  const float* bpost = (const float*)d_in[6];
  float* out = (float*)d_out;
  char* ws = (char*)d_ws;

  unsigned short* adT = (unsigned short*)ws;                       // 16777216 B
  unsigned short* WT1 = (unsigned short*)(ws + 16777216);          // 294912 B
  unsigned short* WT2 = (unsigned short*)(ws + 16777216 + 294912); // 18432 B
  float*          S   = (float*)(ws + 16777216 + 294912 + 18432);  // 2097152 B

  k_weights<<<576, 256, 0, stream>>>(Watt, Wpost, WT1, WT2);
  k_gemm1<<<512, 256, 0, stream>>>(feat, WT1, batt, depth, adT);
  k_borders<<<2048, 256, 0, stream>>>(gts, S, out);
  k_gemm2<<<256, 512, 0, stream>>>(adT, WT2, bpost, (const f32x4*)S, out);
}

// Round 10
// 87.976 us; speedup vs baseline: 1.4605x; 1.4605x over previous
//
#include <hip/hip_runtime.h>
#include <hip/hip_bf16.h>

// VarFlowLoss on MI355X (gfx950) — round 10
// gemm1 = r7 structure + three fixes:
//  (1) A-gather via global_load_dwordx4 (1KB/instruction; was 256B scalar dwords) —
//      bytes-in-flight per CU goes 4x, attacking the measured 1.4 TB/s BW wall.
//  (2) A-LDS rows padded to 80B ([6][66][5 slots]) -> bank-quad (5*xp+g)%8 spreads all
//      8 quads on BOTH the new write pattern and the fragment reads. No XOR needed.
//  (3) loads(c+1) issued before compute(c); barriers drain completed/L2-hot VMEM only.
// B restaged per chunk via source-swizzled glds (r7, proven 0-conflict). 67.7KB -> 2 blk/CU.

typedef __attribute__((ext_vector_type(4))) float f32x4;
typedef __attribute__((ext_vector_type(8))) short s16x8;
typedef __attribute__((ext_vector_type(4))) unsigned int u32x4;

#define DEVFN __device__ __forceinline__

DEVFN float bf2f(unsigned short u){
  unsigned int x = ((unsigned int)u) << 16;
  float f; __builtin_memcpy(&f, &x, 4); return f;
}
DEVFN unsigned short f2bf(float f){
  unsigned int x; __builtin_memcpy(&x, &f, 4);
  x += 0x7fffu + ((x >> 16) & 1u);   // RNE
  return (unsigned short)(x >> 16);
}
DEVFN unsigned cvtpk(float lo, float hi){
  unsigned r;
  asm("v_cvt_pk_bf16_f32 %0, %1, %2" : "=v"(r) : "v"(lo), "v"(hi));
  return r;
}

#define ASYNC16(gp, lp) __builtin_amdgcn_global_load_lds( \
    (const __attribute__((address_space(1))) unsigned int*)(gp), \
    (__attribute__((address_space(3))) unsigned int*)(lp), 16, 0, 0)

// ---------------- weights transform ----------------
__global__ void k_weights(const float* __restrict__ Watt, const float* __restrict__ Wpost,
                          unsigned short* __restrict__ WT1, unsigned short* __restrict__ WT2){
  const int t = blockIdx.x * 256 + threadIdx.x;
  const int n1 = 9 * 64 * 256;
  if (t < n1){
    const int tap = t / (64 * 256);
    const int rem = t % (64 * 256);
    const int oc = rem / 256, ic = rem % 256;
    WT1[t] = f2bf(Watt[(oc * 256 + ic) * 9 + tap]);
  }
  const int n2 = 9 * 16 * 64;
  if (t < n2){
    const int tap = t / (16 * 64);
    const int rem = t % (16 * 64);
    const int od = rem / 64, ic = rem % 64;
    const float v = (od < 10) ? Wpost[(od * 64 + ic) * 9 + tap] : 0.0f;
    WT2[t] = f2bf(v);
  }
}

// ---------------- borders: out=0 + patch border log-sums ----------------
__global__ void k_borders(const float* __restrict__ gts, float* __restrict__ S,
                          float* __restrict__ out){
  const int bid = blockIdx.x, tid = threadIdx.x;
  if (bid == 0 && tid == 0) *out = 0.0f;
  __shared__ float slab[4096];
  const int rel = bid;                  // = b*64 + py
  const float* gp = gts + (size_t)rel * 4096;
#pragma unroll
  for (int it = 0; it < 4; ++it){
    const int id = it * 256 + tid;
    *(f32x4*)&slab[id * 4] = *(const f32x4*)&gp[id * 4];
  }
  __syncthreads();
  const int px = tid & 63, border = tid >> 6;   // border wave-uniform
  float s = 0.0f;
#pragma unroll
  for (int i = 0; i < 8; ++i){
    float v;
    if (border == 0)      v = slab[px * 8 + i];
    else if (border == 1) v = slab[7 * 512 + px * 8 + i];
    else if (border == 2) v = slab[i * 512 + px * 8];
    else                  v = slab[i * 512 + px * 8 + 7];
    v = ((v > 0.1f) && (v < 80.0f)) ? v : 0.0f;
    s += __logf(v + 1e-6f);
  }
  S[((size_t)rel * 64 + px) * 4 + border] = s;
}

// ---------------- GEMM1: fused transpose + att conv + sigmoid * depth ----------------
// 512 blocks x 256 threads (4 waves). BM=256 (4 y-rows), BK=32, 8 chunks.
// A: [6 yy][66 xp][40 shorts(80B row: 5 slots, 4 used)], zero cols xp=0,65; reg-staged
//    fp32->bf16 via dwordx4 + cvt_pk. Row yy staged by wave yy&3 (waves 0,1 take 4,5).
// B: [576 rows][32 ic] via source-swizzled global_load_lds (r7, 0-conflict).
// Schedule: issue loadA(c+1) -> compute(c) -> bar -> cvtWrite(c+1)+stageB(c+1) -> bar.
__global__ __launch_bounds__(256, 2) void k_gemm1(
    const float* __restrict__ feat,             // NCHW fp32 [B][256][64][64]
    const unsigned short* __restrict__ WT1,     // [9][64][256]
    const float* __restrict__ batt,
    const float* __restrict__ depth,            // NCHW fp32 [B][64][64][64]
    unsigned short* __restrict__ adT)           // [B*4096][64]
{
  __shared__ unsigned short As[6 * 66 * 40];   // 31680 B
  __shared__ unsigned short Bs[576 * 32];      // 36864 B
  const int t = threadIdx.x;
  const int l = t & 63, w = t >> 6;
  const int b = blockIdx.x >> 4, ytile = blockIdx.x & 15;
  const int y0 = ytile * 4;
  const int fr = l & 15, g = l >> 4;           // x-quad / ic-octet (= MFMA row / k-octet)

  f32x4 acc[4][4];
#pragma unroll
  for (int i = 0; i < 4; ++i)
#pragma unroll
    for (int j = 0; j < 4; ++j)
#pragma unroll
      for (int q = 0; q < 4; ++q) acc[i][j][q] = 0.0f;

  // zero x-halo columns (xp=0,65): 48 thr = 6 yy x 2 xp x 4 slots
  if (t < 48){
    const int yy = t >> 3, k = t & 7;
    const int xp = (k & 1) ? 65 : 0;
    u32x4 z = {0, 0, 0, 0};
    *(u32x4*)&As[(yy * 66 + xp) * 40 + ((k >> 1) & 3) * 8] = z;
  }

  // load one y-row's (x-quad fr, ic-octet g) fp32: 8 dwordx4, 1KB/instruction wave-wide
  auto loadRow = [&](int c, int yy, f32x4* v){
    const int yr = y0 - 1 + yy;
    if (yr >= 0 && yr < 64){
      const float* gp = feat + ((size_t)(b * 256 + c * 32 + g * 8)) * 4096
                             + (size_t)yr * 64 + fr * 4;
#pragma unroll
      for (int e = 0; e < 8; ++e) v[e] = *(const f32x4*)(gp + (size_t)e * 4096);
    } else {
#pragma unroll
      for (int e = 0; e < 8; ++e) v[e] = f32x4{0.f, 0.f, 0.f, 0.f};
    }
  };
  // cvt_pk 8 f32x4 -> 4 b128 slots (8 consecutive ic each) and write row yy
  auto cvtWriteRow = [&](int yy, const f32x4* v){
#pragma unroll
    for (int o = 0; o < 4; ++o){
      const int xp = fr * 4 + o + 1;
      u32x4 pk;
      pk[0] = cvtpk(v[0][o], v[1][o]);
      pk[1] = cvtpk(v[2][o], v[3][o]);
      pk[2] = cvtpk(v[4][o], v[5][o]);
      pk[3] = cvtpk(v[6][o], v[7][o]);
      *(u32x4*)&As[(yy * 66 + xp) * 40 + g * 8] = pk;
    }
  };
  auto stageB = [&](int c){
#pragma unroll
    for (int it = 0; it < 9; ++it){
      const int idx = it * 256 + t;
      const int row = idx >> 2;
      const int sg = (idx & 3) ^ ((row >> 1) & 3);   // source-slot swizzle
      ASYNC16(WT1 + (size_t)row * 256 + c * 32 + sg * 8, &Bs[(size_t)idx * 8]);
    }
  };
  auto compute = [&](){
    const int slotB = (g ^ ((fr >> 1) & 3)) * 8;
#pragma unroll
    for (int tap = 0; tap < 9; ++tap){
      const int dy = tap / 3 - 1, dxp = tap % 3;     // dx+1
      const int yy = w + dy + 1;
      s16x8 af[4], bfr[4];
#pragma unroll
      for (int i = 0; i < 4; ++i)
        af[i] = *(const s16x8*)&As[(yy * 66 + (i * 16 + fr + dxp)) * 40 + g * 8];
#pragma unroll
      for (int j = 0; j < 4; ++j)
        bfr[j] = *(const s16x8*)&Bs[(tap * 64 + j * 16 + fr) * 32 + slotB];
#pragma unroll
      for (int i = 0; i < 4; ++i)
#pragma unroll
        for (int j = 0; j < 4; ++j)
          acc[i][j] = __builtin_amdgcn_mfma_f32_16x16x32_bf16(af[i], bfr[j], acc[i][j], 0, 0, 0);
    }
  };

  // prologue: chunk 0
  f32x4 r0[8], r1[8];
  loadRow(0, w, r0);
  if (w < 2) loadRow(0, 4 + w, r1);
  stageB(0);
  cvtWriteRow(w, r0);
  if (w < 2) cvtWriteRow(4 + w, r1);
  __syncthreads();

  for (int c = 0; c < 8; ++c){
    if (c < 7){
      loadRow(c + 1, w, r0);               // issued early; compute covers latency
      if (w < 2) loadRow(c + 1, 4 + w, r1);
    }
    compute();
    __syncthreads();                       // A/B reads done; A-loads complete by now
    if (c < 7){
      cvtWriteRow(w, r0);
      if (w < 2) cvtWriteRow(4 + w, r1);
      stageB(c + 1);
    }
    __syncthreads();                       // writes + B glds visible (~L2-hot drain)
  }

  // epilogue: att = sigmoid(acc + b); adT = att * depth
  const int y = y0 + w;
#pragma unroll
  for (int j = 0; j < 4; ++j){
    const int oc = j * 16 + fr;
    const float bb = batt[oc];
    const float* dpt = depth + ((size_t)(b * 64 + oc)) * 4096 + (size_t)y * 64;
    unsigned short* op = adT + ((size_t)(b * 4096 + y * 64)) * 64 + oc;
#pragma unroll
    for (int i = 0; i < 4; ++i){
      const f32x4 dv4 = *(const f32x4*)&dpt[i * 16 + g * 4];
#pragma unroll
      for (int q = 0; q < 4; ++q){
        const int xo = i * 16 + g * 4 + q;
        const float v = acc[i][j][q] + bb;
        const float att = 1.0f / (1.0f + __expf(-v));
        op[(size_t)xo * 64] = f2bf(att * dv4[q]);
      }
    }
  }
}

// ---------------- GEMM2: post conv + fused smooth-L1 loss ----------------
DEVFN float sel4(f32x4 v, int i){
  const float ab = (i & 1) ? v[1] : v[0];
  const float cd = (i & 1) ? v[3] : v[2];
  return (i & 2) ? cd : ab;
}

__global__ __launch_bounds__(512, 2) void k_gemm2(
    const unsigned short* __restrict__ adT,     // [B*4096][64]
    const unsigned short* __restrict__ WT2,     // [9][16][64]
    const float* __restrict__ bpost,
    const f32x4* __restrict__ S,                // [B*4096] {Sn,Ss,Sw,Se}
    float* __restrict__ out)
{
  __shared__ unsigned short As[2][20480];   // 80 KB, source-swizzled
  __shared__ unsigned short Bs[9216];       // full B resident (18 KB), source-swizzled
  __shared__ float ps[8];
  const int t = threadIdx.x;
  const int l = t & 63, w = t >> 6;
  const int b = blockIdx.x >> 3, ytile = blockIdx.x & 7;
  const int y0 = ytile * 8;
  const int fr = l & 15, g = l >> 4;

  f32x4 acc[4];
#pragma unroll
  for (int i = 0; i < 4; ++i)
#pragma unroll
    for (int q = 0; q < 4; ++q) acc[i][q] = 0.0f;

  auto stageA = [&](int c, int d){
#pragma unroll
    for (int it2 = 0; it2 < 5; ++it2){
      const int it = it2 * 2 + (t >> 8);
      const int yy = y0 - 1 + it;
      const int xx = (t >> 2) & 63, icg = t & 3;
      unsigned short* lp = &As[d][(it * 64 + xx) * 32 + icg * 8];
      if (yy >= 0 && yy < 64){
        const int sg = icg ^ ((xx >> 1) & 3);        // source-slot swizzle
        const unsigned short* gp = adT
            + ((size_t)(b * 4096 + yy * 64 + xx)) * 64 + c * 32 + sg * 8;
        ASYNC16(gp, lp);
      } else {
        s16x8 z = {0,0,0,0,0,0,0,0};
        *(s16x8*)lp = z;
      }
    }
  };
  // stage all of B once (144 rows x 128B), 16B slots XOR'd by row&7
#pragma unroll
  for (int it = 0; it < 3; ++it){
    const int idx = it * 512 + t;
    if (idx < 1152){
      const int row = idx >> 3, p = idx & 7;
      const int sg = p ^ (row & 7);
      ASYNC16(WT2 + (size_t)row * 64 + sg * 8, Bs + (size_t)idx * 8);
    }
  }
  stageA(0, 0);
  __syncthreads();

  for (int c = 0; c < 2; ++c){
    if (c == 0) stageA(1, 1);
    const unsigned short* Ab = As[c];
    const int pB = ((c * 4 + g) ^ (fr & 7)) * 8;
    for (int tap = 0; tap < 9; ++tap){
      const int dy = tap / 3 - 1, dx = tap % 3 - 1;
      s16x8 af[4];
#pragma unroll
      for (int i = 0; i < 4; ++i){
        const int xv = i * 16 + fr + dx;
        const bool valid = (xv >= 0) && (xv < 64);
        const int xw = valid ? xv : 0;
        const int slot = (g ^ ((xw >> 1) & 3)) * 8;
        s16x8 v = *(const s16x8*)&Ab[((w + dy + 1) * 64 + xw) * 32 + slot];
        s16x8 z = {0,0,0,0,0,0,0,0};
        af[i] = valid ? v : z;
      }
      const s16x8 bfr = *(const s16x8*)&Bs[(tap * 16 + fr) * 64 + pB];
#pragma unroll
      for (int i = 0; i < 4; ++i)
        acc[i] = __builtin_amdgcn_mfma_f32_16x16x32_bf16(af[i], bfr, acc[i], 0, 0, 0);
    }
    __syncthreads();
  }

  // fused loss epilogue
  const unsigned aPack = (3u<<0)|(1u<<2)|(3u<<4)|(1u<<6)|(2u<<8)|(0u<<10)|(1u<<12)|(3u<<14)|(0u<<16)|(2u<<18);
  const unsigned bPack = (2u<<0)|(0u<<2)|(3u<<4)|(1u<<6)|(2u<<8)|(0u<<10)|(1u<<12)|(3u<<14)|(0u<<16)|(2u<<18);
  float lsum = 0.0f;
  const int y = y0 + w;
  if (fr < 10){
    const int od = fr;
    const int ai = (aPack >> (2 * od)) & 3;
    const int bi = (bPack >> (2 * od)) & 3;
    const bool xshift = (od & 1) == 0;
    const float bp = bpost[od];
#pragma unroll
    for (int i = 0; i < 4; ++i){
#pragma unroll
      for (int q = 0; q < 4; ++q){
        const int xo = i * 16 + g * 4 + q;
        const size_t gm = (size_t)b * 4096 + (size_t)y * 64 + xo;
        const f32x4 sa = S[gm];
        const bool nb = xshift ? (xo < 63) : (y < 63);
        const size_t ga = xshift ? (nb ? gm + 1 : gm) : (nb ? gm + 64 : gm);
        const f32x4 sbv = S[ga];
        const float sbf = nb ? sel4(sbv, bi) : 0.0f;
        const float flow = (sel4(sa, ai) - sbf) * 0.125f;
        const float dv = acc[i][q] + bp - flow;
        const float adv = fabsf(dv);
        lsum += (adv < 0.01f) ? (50.0f * dv * dv) : (adv - 0.005f);
      }
    }
  }
#pragma unroll
  for (int off = 32; off > 0; off >>= 1) lsum += __shfl_down(lsum, off);
  if (l == 0) ps[w] = lsum;
  __syncthreads();
  if (t == 0){
    float s = 0.0f;
#pragma unroll
    for (int i = 0; i < 8; ++i) s += ps[i];
    atomicAdd(out, s * (1.0f / 1310720.0f));
  }
}

// ---------------- launch ----------------
extern "C" void kernel_launch(void* const* d_in, const int* in_sizes, int n_in,
                              void* d_out, int out_size, void* d_ws, size_t ws_size,
                              hipStream_t stream){
  const float* feat  = (const float*)d_in[0];
  const float* depth = (const float*)d_in[1];
  const float* gts   = (const float*)d_in[2];
  const float* Watt  = (const float*)d_in[3];
  const float* batt  = (const float*)d_in[4];
  const float* Wpost = (const float*)d_in[5];
  const float* bpost = (const float*)d_in[6];
  float* out = (float*)d_out;
  char* ws = (char*)d_ws;

  unsigned short* adT = (unsigned short*)ws;                       // 16777216 B
  unsigned short* WT1 = (unsigned short*)(ws + 16777216);          // 294912 B
  unsigned short* WT2 = (unsigned short*)(ws + 16777216 + 294912); // 18432 B
  float*          S   = (float*)(ws + 16777216 + 294912 + 18432);  // 2097152 B

  k_weights<<<576, 256, 0, stream>>>(Watt, Wpost, WT1, WT2);
  k_gemm1<<<512, 256, 0, stream>>>(feat, WT1, batt, depth, adT);
  k_borders<<<2048, 256, 0, stream>>>(gts, S, out);
  k_gemm2<<<256, 512, 0, stream>>>(adT, WT2, bpost, (const f32x4*)S, out);
}